// Round 14
// baseline (364.081 us; speedup 1.0000x reference)
//
#include <hip/hip_runtime.h>

#define NS 16384            // samples
#define ED 128              // embed dim
#define KC 10000            // clusters
#define KP 10240            // padded clusters (80 * 128)
#define EKTOT (ED*KC)       // 1280000

// d_out layout (floats, concatenated in return order)
#define O_OUT  0
#define O_LOSS (NS*ED)              // 2097152
#define O_MEAN (O_LOSS+1)           // 2097153
#define O_SIZE (O_MEAN+EKTOT)       // 3377153
#define O_SUM  (O_SIZE+KC)          // 3387153
// sumT scratch = out[0 .. KC*ED) : dead until k_gather overwrites (runs after k_mean)

// ws byte offsets (peak 13.93 MB)
#define WB_BEST  0u          // NS * u64
#define WB_CNORM 131072u     // KP * f32
#define WB_IDX   172032u     // NS * i32
#define WB_CNT   237568u     // KP * f32
#define WB_NS    278528u     // 1 * f32  (sum of input cluster_size)
#define WB_XH    294912u     // NS*ED f16   (meanT overlays XH/XL after k_assign)
#define WB_XL    4489216u    // NS*ED f16
#define WB_MH    8683520u    // KP*ED f16 (transposed: [cluster][e])
#define WB_ML    11304960u   // KP*ED f16

typedef _Float16 f16;
typedef _Float16 f16x8 __attribute__((ext_vector_type(8)));
typedef _Float16 f16x4 __attribute__((ext_vector_type(4)));
typedef float f32x4 __attribute__((ext_vector_type(4)));

constexpr float DECAY = 0.99f;
constexpr float OMD   = 0.01f;   // 1 - DECAY
constexpr float EPSV  = 1e-5f;

// Fused prep (R5-proven): blocks [0,2048) splitX + zero sumT slice;
// [2048,2088) splitM + zero cnt/best; block 2088: CZ-sum + loss zero.
__global__ void k_prep(const float* __restrict__ X, const float* __restrict__ M,
                       const float* __restrict__ CZ,
                       f16* __restrict__ Xh, f16* __restrict__ Xl,
                       f16* __restrict__ Mh, f16* __restrict__ Ml,
                       float* __restrict__ cnorm, float* __restrict__ cnt,
                       unsigned long long* __restrict__ best,
                       float* __restrict__ out, float* __restrict__ ns_cz) {
    const int b = blockIdx.x, t = threadIdx.x;
    if (b < 2048) {
        int i = (b * 256 + t) * 4;
        float4 v = *(const float4*)(X + i);
        f16x4 h, l;
        h[0] = (f16)v.x; l[0] = (f16)(v.x - (float)h[0]);
        h[1] = (f16)v.y; l[1] = (f16)(v.y - (float)h[1]);
        h[2] = (f16)v.z; l[2] = (f16)(v.z - (float)h[2]);
        h[3] = (f16)v.w; l[3] = (f16)(v.w - (float)h[3]);
        *(f16x4*)(Xh + i) = h;
        *(f16x4*)(Xl + i) = l;
        if (t < 160) {
            int f4 = b * 160 + t;
            if (f4 * 4 < EKTOT) *(float4*)(out + f4 * 4) = make_float4(0.f, 0.f, 0.f, 0.f);
        }
    } else if (b < 2088) {
        int k = (b - 2048) * 256 + t;            // < KP
        float s = __builtin_inff();
        if (k < KC) {
            s = 0.f;
            #pragma unroll
            for (int c = 0; c < 16; ++c) {
                f16x8 h, l;
                #pragma unroll
                for (int j = 0; j < 8; ++j) {
                    float m = M[(size_t)(c * 8 + j) * KC + k];   // coalesced
                    s = fmaf(m, m, s);
                    h[j] = (f16)m;
                    l[j] = (f16)(m - (float)h[j]);
                }
                *(f16x8*)(Mh + (size_t)k * ED + c * 8) = h;
                *(f16x8*)(Ml + (size_t)k * ED + c * 8) = l;
            }
        } else {
            f16x8 z = {0, 0, 0, 0, 0, 0, 0, 0};
            #pragma unroll
            for (int c = 0; c < 16; ++c) {
                *(f16x8*)(Mh + (size_t)k * ED + c * 8) = z;
                *(f16x8*)(Ml + (size_t)k * ED + c * 8) = z;
            }
        }
        cnorm[k] = s;
        cnt[k] = 0.f;
        for (int i = k; i < NS; i += 40 * 256) best[i] = ~0ull;
    } else {
        __shared__ float red[256];
        float s = 0.f;
        for (int i = t; i < KC; i += 256) s += CZ[i];
        red[t] = s;
        __syncthreads();
        for (int st = 128; st > 0; st >>= 1) {
            if (t < st) red[t] += red[t + st];
            __syncthreads();
        }
        if (t == 0) { *ns_cz = red[0]; out[O_LOSS] = 0.f; }
    }
}

// MFMA assign (R5-proven verbatim): D[n][c] = X[n]·M[c], 3-pair fp16 split,
// 128x128 tile, BK=64, 4 waves, global_load_lds, T2 XOR swizzle, A-skip at
// st=1,4. 32KB LDS, VGPR 64, ~4 blocks/CU — best measured (243 us).
__launch_bounds__(256, 4)
__global__ void k_assign(const f16* __restrict__ Xh, const f16* __restrict__ Xl,
                         const f16* __restrict__ Mh, const f16* __restrict__ Ml,
                         const float* __restrict__ cnorm,
                         unsigned long long* __restrict__ best) {
    __shared__ f16 As[128 * 64];   // 16KB
    __shared__ f16 Bs[128 * 64];   // 16KB

    const int c0 = blockIdx.x * 128;   // 80 col-blocks
    const int n0 = blockIdx.y * 128;   // 128 row-blocks
    const int t = threadIdx.x, w = t >> 6, l = t & 63;
    const int wr = w >> 1, wc = w & 1;
    const int lg = l >> 4, li = l & 15;

    f32x4 acc[4][4];
    #pragma unroll
    for (int i = 0; i < 4; ++i)
        #pragma unroll
        for (int j = 0; j < 4; ++j) acc[i][j] = (f32x4)0.f;

    // stage order: (Xh,Mh),(Xh,Ml),(Xl,Mh) per K-half -> A unchanged at st=1,4
    const f16* Ap[6] = {Xh, Xh, Xl, Xh, Xh, Xl};
    const f16* Bp[6] = {Mh, Ml, Mh, Mh, Ml, Mh};

    for (int st = 0; st < 6; ++st) {
        const int hh = st < 3 ? 0 : 1;
        const bool loadA = (st != 1) && (st != 4);
        const f16* A = Ap[st];
        const f16* B = Bp[st];
        __syncthreads();                        // protect previous reads
        #pragma unroll
        for (int it = 0; it < 4; ++it) {
            int f = it * 256 + t;               // 16B-chunk index 0..1023
            int row = f >> 3, seg = f & 7;
            int segS = seg ^ (row & 7);         // inverse swizzle on SOURCE
            const f16* gb = B + (size_t)(c0 + row) * ED + hh * 64 + segS * 8;
            f16* lb = Bs + (it * 256 + w * 64) * 8;   // wave-uniform base, linear
            __builtin_amdgcn_global_load_lds(
                (const __attribute__((address_space(1))) unsigned int*)gb,
                (__attribute__((address_space(3))) unsigned int*)lb, 16, 0, 0);
            if (loadA) {
                const f16* ga = A + (size_t)(n0 + row) * ED + hh * 64 + segS * 8;
                f16* la = As + (it * 256 + w * 64) * 8;
                __builtin_amdgcn_global_load_lds(
                    (const __attribute__((address_space(1))) unsigned int*)ga,
                    (__attribute__((address_space(3))) unsigned int*)la, 16, 0, 0);
            }
        }
        __syncthreads();
        #pragma unroll
        for (int ks = 0; ks < 2; ++ks) {
            f16x8 a[4], b[4];
            #pragma unroll
            for (int i = 0; i < 4; ++i) {
                int r = wr * 64 + i * 16 + li;
                a[i] = *(const f16x8*)(As + r * 64 + ((ks * 32 + lg * 8) ^ ((r & 7) << 3)));
            }
            #pragma unroll
            for (int j = 0; j < 4; ++j) {
                int r = wc * 64 + j * 16 + li;
                b[j] = *(const f16x8*)(Bs + r * 64 + ((ks * 32 + lg * 8) ^ ((r & 7) << 3)));
            }
            #pragma unroll
            for (int i = 0; i < 4; ++i)
                #pragma unroll
                for (int j = 0; j < 4; ++j)
                    acc[i][j] = __builtin_amdgcn_mfma_f32_16x16x32_f16(a[i], b[j], acc[i][j], 0, 0, 0);
        }
    }

    // argmin epilogue: d = |m|^2 - 2 x·m ; C/D layout col=li, row=lg*4+reg
    float cn[4];
    #pragma unroll
    for (int j = 0; j < 4; ++j) cn[j] = cnorm[c0 + wc * 64 + j * 16 + li];

    #pragma unroll
    for (int i = 0; i < 4; ++i) {
        #pragma unroll
        for (int r = 0; r < 4; ++r) {
            float bv = __builtin_inff(); int bc = 0;
            #pragma unroll
            for (int j = 0; j < 4; ++j) {
                int c = c0 + wc * 64 + j * 16 + li;
                float d = fmaf(-2.f, acc[i][j][r], cn[j]);
                if (d < bv) { bv = d; bc = c; }   // ascending c: first-min kept
            }
            #pragma unroll
            for (int off = 1; off < 16; off <<= 1) {
                float v2 = __shfl_xor(bv, off);
                int   c2 = __shfl_xor(bc, off);
                if (v2 < bv || (v2 == bv && c2 < bc)) { bv = v2; bc = c2; }
            }
            if (li == 0) {
                unsigned u = __float_as_uint(bv);
                u = (u & 0x80000000u) ? ~u : (u | 0x80000000u);  // order-preserving
                unsigned long long key = ((unsigned long long)u << 32) | (unsigned)bc;
                atomicMin(best + (n0 + wr * 64 + i * 16 + lg * 4 + r), key);
            }
        }
    }
}

// scatter + idx extraction: sumT[k][e] transposed accumulation
__global__ void k_scatter(const float* __restrict__ X,
                          const unsigned long long* __restrict__ best,
                          int* __restrict__ idx,
                          float* __restrict__ sumT, float* __restrict__ cnt) {
    int tt = blockIdx.x * 256 + threadIdx.x;
    int n = tt >> 7, e = tt & 127;
    int k = (int)(unsigned)(best[n] & 0xFFFFFFFFull);
    if (e == 0) { idx[n] = k; atomicAdd(cnt + k, 1.0f); }
    atomicAdd(sumT + (size_t)k * ED + e, X[tt] * OMD);
}

// mean + size fused; 4-way e-chunked 64k x 32e LDS-transpose tiles;
// per-element arithmetic identical (no reductions).
__global__ void k_mean(const float* __restrict__ csum, const float* __restrict__ csize,
                       const float* __restrict__ cnt, const float* __restrict__ ns_cz,
                       float* __restrict__ out, float* __restrict__ meanT) {
    __shared__ float lds[64 * 33];
    const int kb = blockIdx.x >> 2, ch = blockIdx.x & 3;
    const int k0 = kb * 64, e0 = ch * 32;
    const int t = threadIdx.x;
    const float* sumT = out;                    // [KC][ED] scratch in O_OUT region

    #pragma unroll
    for (int r = 0; r < 8; ++r) {               // load sumT tile (coalesced)
        int f = r * 256 + t;
        int kl = f >> 5, el = f & 31;
        float v = (k0 + kl < KC) ? sumT[(size_t)(k0 + kl) * ED + e0 + el] : 0.f;
        lds[kl * 33 + el] = v;
    }
    __syncthreads();

    const int kl2 = t & 63, ww = t >> 6;
    const int k = k0 + kl2;
    if (k < KC) {
        float nsz = fmaf(csize[k], DECAY, cnt[k] * OMD);
        if (ch == 0 && ww == 0) out[O_SIZE + k] = nsz;
        float ns  = fmaf(*ns_cz, DECAY, OMD * (float)NS);   // = sum(new_cluster_size)
        float sm  = (nsz + EPSV) * ns / (ns + (float)KC * EPSV);
        float inv = 1.f / sm;
        #pragma unroll
        for (int r2 = 0; r2 < 8; ++r2) {
            int e2 = e0 + r2 * 4 + ww;
            float s   = lds[kl2 * 33 + (e2 - e0)];
            float ncs = fmaf(csum[(size_t)e2 * KC + k], DECAY, s);
            out[O_SUM  + (size_t)e2 * KC + k] = ncs;      // coalesced
            float mean = ncs * inv;
            out[O_MEAN + (size_t)e2 * KC + k] = mean;     // coalesced
            lds[kl2 * 33 + (e2 - e0)] = mean;             // in-place, same slot
        }
    }
    __syncthreads();

    #pragma unroll
    for (int r = 0; r < 8; ++r) {               // write meanT (coalesced)
        int f = r * 256 + t;
        int kl = f >> 5, el = f & 31;
        if (k0 + kl < KC) meanT[(size_t)(k0 + kl) * ED + e0 + el] = lds[kl * 33 + el];
    }
}

__global__ void k_gather(const float* __restrict__ X, const int* __restrict__ idx,
                         const float* __restrict__ meanT, float* __restrict__ out) {
    __shared__ float red[256];
    int tt = blockIdx.x * 256 + threadIdx.x;
    int n = tt >> 7, e = tt & 127;
    int k = idx[n];
    float q = meanT[(size_t)k * ED + e];        // coalesced
    float x = X[tt];
    out[O_OUT + tt] = x + (q - x);
    float d = x - q;
    red[threadIdx.x] = d * d;
    __syncthreads();
    for (int s = 128; s > 0; s >>= 1) {
        if (threadIdx.x < s) red[threadIdx.x] += red[threadIdx.x + s];
        __syncthreads();
    }
    if (threadIdx.x == 0)
        atomicAdd(out + O_LOSS, red[0] * (0.25f / (float)(NS * ED)));
}

extern "C" void kernel_launch(void* const* d_in, const int* in_sizes, int n_in,
                              void* d_out, int out_size, void* d_ws, size_t ws_size,
                              hipStream_t stream) {
    const float* X  = (const float*)d_in[0];   // inputs [16384,128]
    const float* M  = (const float*)d_in[1];   // cluster_mean [128,10000]
    const float* CS = (const float*)d_in[2];   // cluster_sum  [128,10000]
    const float* CZ = (const float*)d_in[3];   // cluster_size [10000]
    float* out = (float*)d_out;

    char* wsb = (char*)d_ws;
    unsigned long long* best = (unsigned long long*)(wsb + WB_BEST);
    float* cnorm = (float*)(wsb + WB_CNORM);
    int*   idx   = (int*)(wsb + WB_IDX);
    float* cnt   = (float*)(wsb + WB_CNT);
    float* ns_cz = (float*)(wsb + WB_NS);
    f16* Xh = (f16*)(wsb + WB_XH);
    f16* Xl = (f16*)(wsb + WB_XL);
    f16* Mh = (f16*)(wsb + WB_MH);
    f16* Ml = (f16*)(wsb + WB_ML);
    float* sumT  = out;                        // O_OUT region scratch
    float* meanT = (float*)(wsb + WB_XH);      // overlays Xh/Xl (dead after k_assign)

    hipLaunchKernelGGL(k_prep,   dim3(2089),               dim3(256), 0, stream,
                       X, M, CZ, Xh, Xl, Mh, Ml, cnorm, cnt, best, out, ns_cz);
    hipLaunchKernelGGL(k_assign, dim3(KP / 128, NS / 128), dim3(256), 0, stream,
                       Xh, Xl, Mh, Ml, cnorm, best);
    hipLaunchKernelGGL(k_scatter,dim3(NS * ED / 256),      dim3(256), 0, stream,
                       X, best, idx, sumT, cnt);
    hipLaunchKernelGGL(k_mean,   dim3(((KC + 63) / 64) * 4), dim3(256), 0, stream,
                       CS, CZ, cnt, ns_cz, out, meanT);
    hipLaunchKernelGGL(k_gather, dim3(NS * ED / 256),      dim3(256), 0, stream,
                       X, idx, meanT, out);
}

// Round 16
// 356.261 us; speedup vs baseline: 1.0219x; 1.0219x over previous
//
#include <hip/hip_runtime.h>

#define NS 16384            // samples
#define ED 128              // embed dim
#define KC 10000            // clusters
#define KP 10240            // padded clusters (80 * 128)
#define EKTOT (ED*KC)       // 1280000

// d_out layout (floats, concatenated in return order)
#define O_OUT  0
#define O_LOSS (NS*ED)              // 2097152
#define O_MEAN (O_LOSS+1)           // 2097153
#define O_SIZE (O_MEAN+EKTOT)       // 3377153
#define O_SUM  (O_SIZE+KC)          // 3387153
// sumT scratch = out[0 .. KC*ED) : dead until k_gather overwrites (runs after k_mean)

// ws byte offsets (peak 13.93 MB)
#define WB_BEST  0u          // NS * u64
#define WB_CNORM 131072u     // KP * f32
#define WB_IDX   172032u     // NS * i32
#define WB_CNT   237568u     // KP * f32
#define WB_NS    278528u     // 1 * f32  (sum of input cluster_size)
#define WB_XH    294912u     // NS*ED f16   (meanT overlays XH/XL after k_assign)
#define WB_XL    4489216u    // NS*ED f16
#define WB_MH    8683520u    // KP*ED f16 (transposed: [cluster][e])
#define WB_ML    11304960u   // KP*ED f16

typedef _Float16 f16;
typedef _Float16 f16x8 __attribute__((ext_vector_type(8)));
typedef _Float16 f16x4 __attribute__((ext_vector_type(4)));
typedef float f32x4 __attribute__((ext_vector_type(4)));

constexpr float DECAY = 0.99f;
constexpr float OMD   = 0.01f;   // 1 - DECAY
constexpr float EPSV  = 1e-5f;

// Fused prep (R5-proven): blocks [0,2048) splitX + zero sumT slice;
// [2048,2088) splitM + zero cnt/best; block 2088: CZ-sum + loss zero.
__global__ void k_prep(const float* __restrict__ X, const float* __restrict__ M,
                       const float* __restrict__ CZ,
                       f16* __restrict__ Xh, f16* __restrict__ Xl,
                       f16* __restrict__ Mh, f16* __restrict__ Ml,
                       float* __restrict__ cnorm, float* __restrict__ cnt,
                       unsigned long long* __restrict__ best,
                       float* __restrict__ out, float* __restrict__ ns_cz) {
    const int b = blockIdx.x, t = threadIdx.x;
    if (b < 2048) {
        int i = (b * 256 + t) * 4;
        float4 v = *(const float4*)(X + i);
        f16x4 h, l;
        h[0] = (f16)v.x; l[0] = (f16)(v.x - (float)h[0]);
        h[1] = (f16)v.y; l[1] = (f16)(v.y - (float)h[1]);
        h[2] = (f16)v.z; l[2] = (f16)(v.z - (float)h[2]);
        h[3] = (f16)v.w; l[3] = (f16)(v.w - (float)h[3]);
        *(f16x4*)(Xh + i) = h;
        *(f16x4*)(Xl + i) = l;
        if (t < 160) {
            int f4 = b * 160 + t;
            if (f4 * 4 < EKTOT) *(float4*)(out + f4 * 4) = make_float4(0.f, 0.f, 0.f, 0.f);
        }
    } else if (b < 2088) {
        int k = (b - 2048) * 256 + t;            // < KP
        float s = __builtin_inff();
        if (k < KC) {
            s = 0.f;
            #pragma unroll
            for (int c = 0; c < 16; ++c) {
                f16x8 h, l;
                #pragma unroll
                for (int j = 0; j < 8; ++j) {
                    float m = M[(size_t)(c * 8 + j) * KC + k];   // coalesced
                    s = fmaf(m, m, s);
                    h[j] = (f16)m;
                    l[j] = (f16)(m - (float)h[j]);
                }
                *(f16x8*)(Mh + (size_t)k * ED + c * 8) = h;
                *(f16x8*)(Ml + (size_t)k * ED + c * 8) = l;
            }
        } else {
            f16x8 z = {0, 0, 0, 0, 0, 0, 0, 0};
            #pragma unroll
            for (int c = 0; c < 16; ++c) {
                *(f16x8*)(Mh + (size_t)k * ED + c * 8) = z;
                *(f16x8*)(Ml + (size_t)k * ED + c * 8) = z;
            }
        }
        cnorm[k] = s;
        cnt[k] = 0.f;
        for (int i = k; i < NS; i += 40 * 256) best[i] = ~0ull;
    } else {
        __shared__ float red[256];
        float s = 0.f;
        for (int i = t; i < KC; i += 256) s += CZ[i];
        red[t] = s;
        __syncthreads();
        for (int st = 128; st > 0; st >>= 1) {
            if (t < st) red[t] += red[t + st];
            __syncthreads();
        }
        if (t == 0) { *ns_cz = red[0]; out[O_LOSS] = 0.f; }
    }
}

// MFMA assign (R5-proven verbatim): D[n][c] = X[n]·M[c], 3-pair fp16 split,
// 128x128 tile, BK=64, 4 waves, global_load_lds, T2 XOR swizzle, A-skip at
// st=1,4. 32KB LDS, VGPR 64, ~4 blocks/CU — best measured (243 us).
__launch_bounds__(256, 4)
__global__ void k_assign(const f16* __restrict__ Xh, const f16* __restrict__ Xl,
                         const f16* __restrict__ Mh, const f16* __restrict__ Ml,
                         const float* __restrict__ cnorm,
                         unsigned long long* __restrict__ best) {
    __shared__ f16 As[128 * 64];   // 16KB
    __shared__ f16 Bs[128 * 64];   // 16KB

    const int c0 = blockIdx.x * 128;   // 80 col-blocks
    const int n0 = blockIdx.y * 128;   // 128 row-blocks
    const int t = threadIdx.x, w = t >> 6, l = t & 63;
    const int wr = w >> 1, wc = w & 1;
    const int lg = l >> 4, li = l & 15;

    f32x4 acc[4][4];
    #pragma unroll
    for (int i = 0; i < 4; ++i)
        #pragma unroll
        for (int j = 0; j < 4; ++j) acc[i][j] = (f32x4)0.f;

    // stage order: (Xh,Mh),(Xh,Ml),(Xl,Mh) per K-half -> A unchanged at st=1,4
    const f16* Ap[6] = {Xh, Xh, Xl, Xh, Xh, Xl};
    const f16* Bp[6] = {Mh, Ml, Mh, Mh, Ml, Mh};

    for (int st = 0; st < 6; ++st) {
        const int hh = st < 3 ? 0 : 1;
        const bool loadA = (st != 1) && (st != 4);
        const f16* A = Ap[st];
        const f16* B = Bp[st];
        __syncthreads();                        // protect previous reads
        #pragma unroll
        for (int it = 0; it < 4; ++it) {
            int f = it * 256 + t;               // 16B-chunk index 0..1023
            int row = f >> 3, seg = f & 7;
            int segS = seg ^ (row & 7);         // inverse swizzle on SOURCE
            const f16* gb = B + (size_t)(c0 + row) * ED + hh * 64 + segS * 8;
            f16* lb = Bs + (it * 256 + w * 64) * 8;   // wave-uniform base, linear
            __builtin_amdgcn_global_load_lds(
                (const __attribute__((address_space(1))) unsigned int*)gb,
                (__attribute__((address_space(3))) unsigned int*)lb, 16, 0, 0);
            if (loadA) {
                const f16* ga = A + (size_t)(n0 + row) * ED + hh * 64 + segS * 8;
                f16* la = As + (it * 256 + w * 64) * 8;
                __builtin_amdgcn_global_load_lds(
                    (const __attribute__((address_space(1))) unsigned int*)ga,
                    (__attribute__((address_space(3))) unsigned int*)la, 16, 0, 0);
            }
        }
        __syncthreads();
        #pragma unroll
        for (int ks = 0; ks < 2; ++ks) {
            f16x8 a[4], b[4];
            #pragma unroll
            for (int i = 0; i < 4; ++i) {
                int r = wr * 64 + i * 16 + li;
                a[i] = *(const f16x8*)(As + r * 64 + ((ks * 32 + lg * 8) ^ ((r & 7) << 3)));
            }
            #pragma unroll
            for (int j = 0; j < 4; ++j) {
                int r = wc * 64 + j * 16 + li;
                b[j] = *(const f16x8*)(Bs + r * 64 + ((ks * 32 + lg * 8) ^ ((r & 7) << 3)));
            }
            #pragma unroll
            for (int i = 0; i < 4; ++i)
                #pragma unroll
                for (int j = 0; j < 4; ++j)
                    acc[i][j] = __builtin_amdgcn_mfma_f32_16x16x32_f16(a[i], b[j], acc[i][j], 0, 0, 0);
        }
    }

    // argmin epilogue: d = |m|^2 - 2 x·m ; C/D layout col=li, row=lg*4+reg
    float cn[4];
    #pragma unroll
    for (int j = 0; j < 4; ++j) cn[j] = cnorm[c0 + wc * 64 + j * 16 + li];

    #pragma unroll
    for (int i = 0; i < 4; ++i) {
        #pragma unroll
        for (int r = 0; r < 4; ++r) {
            float bv = __builtin_inff(); int bc = 0;
            #pragma unroll
            for (int j = 0; j < 4; ++j) {
                int c = c0 + wc * 64 + j * 16 + li;
                float d = fmaf(-2.f, acc[i][j][r], cn[j]);
                if (d < bv) { bv = d; bc = c; }   // ascending c: first-min kept
            }
            #pragma unroll
            for (int off = 1; off < 16; off <<= 1) {
                float v2 = __shfl_xor(bv, off);
                int   c2 = __shfl_xor(bc, off);
                if (v2 < bv || (v2 == bv && c2 < bc)) { bv = v2; bc = c2; }
            }
            if (li == 0) {
                unsigned u = __float_as_uint(bv);
                u = (u & 0x80000000u) ? ~u : (u | 0x80000000u);  // order-preserving
                unsigned long long key = ((unsigned long long)u << 32) | (unsigned)bc;
                atomicMin(best + (n0 + wr * 64 + i * 16 + lg * 4 + r), key);
            }
        }
    }
}

// scatter + idx extraction: sumT[k][e] transposed accumulation
__global__ void k_scatter(const float* __restrict__ X,
                          const unsigned long long* __restrict__ best,
                          int* __restrict__ idx,
                          float* __restrict__ sumT, float* __restrict__ cnt) {
    int tt = blockIdx.x * 256 + threadIdx.x;
    int n = tt >> 7, e = tt & 127;
    int k = (int)(unsigned)(best[n] & 0xFFFFFFFFull);
    if (e == 0) { idx[n] = k; atomicAdd(cnt + k, 1.0f); }
    atomicAdd(sumT + (size_t)k * ED + e, X[tt] * OMD);
}

// mean + size fused; 4-way e-chunked 64k x 32e LDS-transpose tiles;
// per-element arithmetic identical (no reductions).
__global__ void k_mean(const float* __restrict__ csum, const float* __restrict__ csize,
                       const float* __restrict__ cnt, const float* __restrict__ ns_cz,
                       float* __restrict__ out, float* __restrict__ meanT) {
    __shared__ float lds[64 * 33];
    const int kb = blockIdx.x >> 2, ch = blockIdx.x & 3;
    const int k0 = kb * 64, e0 = ch * 32;
    const int t = threadIdx.x;
    const float* sumT = out;                    // [KC][ED] scratch in O_OUT region

    #pragma unroll
    for (int r = 0; r < 8; ++r) {               // load sumT tile (coalesced)
        int f = r * 256 + t;
        int kl = f >> 5, el = f & 31;
        float v = (k0 + kl < KC) ? sumT[(size_t)(k0 + kl) * ED + e0 + el] : 0.f;
        lds[kl * 33 + el] = v;
    }
    __syncthreads();

    const int kl2 = t & 63, ww = t >> 6;
    const int k = k0 + kl2;
    if (k < KC) {
        float nsz = fmaf(csize[k], DECAY, cnt[k] * OMD);
        if (ch == 0 && ww == 0) out[O_SIZE + k] = nsz;
        float ns  = fmaf(*ns_cz, DECAY, OMD * (float)NS);   // = sum(new_cluster_size)
        float sm  = (nsz + EPSV) * ns / (ns + (float)KC * EPSV);
        float inv = 1.f / sm;
        #pragma unroll
        for (int r2 = 0; r2 < 8; ++r2) {
            int e2 = e0 + r2 * 4 + ww;
            float s   = lds[kl2 * 33 + (e2 - e0)];
            float ncs = fmaf(csum[(size_t)e2 * KC + k], DECAY, s);
            out[O_SUM  + (size_t)e2 * KC + k] = ncs;      // coalesced
            float mean = ncs * inv;
            out[O_MEAN + (size_t)e2 * KC + k] = mean;     // coalesced
            lds[kl2 * 33 + (e2 - e0)] = mean;             // in-place, same slot
        }
    }
    __syncthreads();

    #pragma unroll
    for (int r = 0; r < 8; ++r) {               // write meanT (coalesced)
        int f = r * 256 + t;
        int kl = f >> 5, el = f & 31;
        if (k0 + kl < KC) meanT[(size_t)(k0 + kl) * ED + e0 + el] = lds[kl * 33 + el];
    }
}

__global__ void k_gather(const float* __restrict__ X, const int* __restrict__ idx,
                         const float* __restrict__ meanT, float* __restrict__ out) {
    __shared__ float red[256];
    int tt = blockIdx.x * 256 + threadIdx.x;
    int n = tt >> 7, e = tt & 127;
    int k = idx[n];
    float q = meanT[(size_t)k * ED + e];        // coalesced
    float x = X[tt];
    out[O_OUT + tt] = x + (q - x);
    float d = x - q;
    red[threadIdx.x] = d * d;
    __syncthreads();
    for (int s = 128; s > 0; s >>= 1) {
        if (threadIdx.x < s) red[threadIdx.x] += red[threadIdx.x + s];
        __syncthreads();
    }
    if (threadIdx.x == 0)
        atomicAdd(out + O_LOSS, red[0] * (0.25f / (float)(NS * ED)));
}

extern "C" void kernel_launch(void* const* d_in, const int* in_sizes, int n_in,
                              void* d_out, int out_size, void* d_ws, size_t ws_size,
                              hipStream_t stream) {
    const float* X  = (const float*)d_in[0];   // inputs [16384,128]
    const float* M  = (const float*)d_in[1];   // cluster_mean [128,10000]
    const float* CS = (const float*)d_in[2];   // cluster_sum  [128,10000]
    const float* CZ = (const float*)d_in[3];   // cluster_size [10000]
    float* out = (float*)d_out;

    char* wsb = (char*)d_ws;
    unsigned long long* best = (unsigned long long*)(wsb + WB_BEST);
    float* cnorm = (float*)(wsb + WB_CNORM);
    int*   idx   = (int*)(wsb + WB_IDX);
    float* cnt   = (float*)(wsb + WB_CNT);
    float* ns_cz = (float*)(wsb + WB_NS);
    f16* Xh = (f16*)(wsb + WB_XH);
    f16* Xl = (f16*)(wsb + WB_XL);
    f16* Mh = (f16*)(wsb + WB_MH);
    f16* Ml = (f16*)(wsb + WB_ML);
    float* sumT  = out;                        // O_OUT region scratch
    float* meanT = (float*)(wsb + WB_XH);      // overlays Xh/Xl (dead after k_assign)

    hipLaunchKernelGGL(k_prep,   dim3(2089),               dim3(256), 0, stream,
                       X, M, CZ, Xh, Xl, Mh, Ml, cnorm, cnt, best, out, ns_cz);
    hipLaunchKernelGGL(k_assign, dim3(KP / 128, NS / 128), dim3(256), 0, stream,
                       Xh, Xl, Mh, Ml, cnorm, best);
    hipLaunchKernelGGL(k_scatter,dim3(NS * ED / 256),      dim3(256), 0, stream,
                       X, best, idx, sumT, cnt);
    hipLaunchKernelGGL(k_mean,   dim3(((KC + 63) / 64) * 4), dim3(256), 0, stream,
                       CS, CZ, cnt, ns_cz, out, meanT);
    hipLaunchKernelGGL(k_gather, dim3(NS * ED / 256),      dim3(256), 0, stream,
                       X, idx, meanT, out);
}